// Round 11
// baseline (37.956 us; speedup 1.0000x reference)
//
#include <hip/hip_runtime.h>

#define MM    32768
#define OUTN  65536
#define NBC   64                  // output blocks of 1024 bins
#define NSTW  16                  // i0-steps (of 32 limbs) per workgroup
#define APL   1536                // revA bytes per digit plane (1504 live, pad)
#define BPL   608                 // B-phase bytes per (plane,phase) (543 live, pad)
#define BOFF  (3 * APL)           // 4608
#define ABSZ  (BOFF + 12 * BPL)   // 11904 bytes of A/B staging
#define TPB   256                 // 4 waves; each wave owns 4 of the 16 steps

typedef int i32x4  __attribute__((ext_vector_type(4)));
typedef int i32x16 __attribute__((ext_vector_type(16)));

// Per output block b (c0 = 1024b): i-sweep start (aligned) and 16-step units.
__host__ __device__ inline void blk_params(int b, int* Istart, int* units) {
    const int c0 = b << 10;
    int iLo = c0 - (MM - 1); if (iLo < 0) iLo = 0;
    int iHi = c0 + 1023;     if (iHi > MM - 1) iHi = MM - 1;
    const int Is = (iLo - 961) & ~31;
    const int Ie = (iHi + 31) & ~31;
    const int steps = ((Ie - Is) >> 5) + 1;
    *Istart = Is;
    *units  = (steps + NSTW - 1) / NSTW;
}

// A-read swizzle (verified R9/R10).
__device__ __forceinline__ int swzA(int a) {
    return a ^ ((a >> 2) & 0x30) ^ ((a >> 4) & 0x30);
}
__device__ __forceinline__ unsigned ldv(const int* __restrict__ p, int x) {
    return ((unsigned)x < (unsigned)MM) ? (unsigned)p[x] : 0u;
}
__device__ __forceinline__ unsigned pk4(unsigned b0, unsigned b1, unsigned b2, unsigned b3) {
    return b0 | (b1 << 8) | (b2 << 16) | (b3 << 24);
}
__device__ __forceinline__ i32x16 z16() {
    i32x16 v;
#pragma unroll
    for (int i = 0; i < 16; ++i) v[i] = 0;
    return v;
}

// DIAGNOSTIC build: the step loop runs TWICE (pass 0 parks into red[] across
// a barrier -> kept live; pass 1 recomputes the identical values that are
// reduced). Output is bit-identical to the single-pass R10 kernel.
template <bool PARTIAL>
__global__ __launch_bounds__(TPB, 4) void conv_mfma(
    const int* __restrict__ A, const int* __restrict__ B,
    unsigned* __restrict__ part, unsigned* __restrict__ out)
{
    __shared__ __align__(16) char lds[ABSZ];      // A/B staging (disjoint)
    __shared__ __align__(16) unsigned red[4096];  // 4 waves x 1024 bins

    int id = (int)blockIdx.x, blk = 0, Istart = 0, un = 0;
#pragma unroll 1
    for (; blk < NBC; ++blk) {
        blk_params(blk, &Istart, &un);
        if (id < un) break;
        id -= un;
    }
    const int c0   = blk << 10;
    const int S0   = Istart + 512 * id;
    const int ATop = S0 + 1472;
    const int JB   = c0 - S0 - 480;
    const int l    = (int)threadIdx.x;

    // ---- Stage A (376 dwords x 3 planes) ----
#pragma unroll
    for (int it = 0; it < 2; ++it) {
        const int w = l + (it << 8);
        if (w < 376) {
            const int x0 = ATop - 4 * w;
            const unsigned v0 = ldv(A, x0),     v1 = ldv(A, x0 - 1);
            const unsigned v2 = ldv(A, x0 - 2), v3 = ldv(A, x0 - 3);
            const int wa = swzA(4 * w);
            *(unsigned*)&lds[0 * APL + wa] = pk4(v0 & 127, v1 & 127, v2 & 127, v3 & 127);
            *(unsigned*)&lds[1 * APL + wa] = pk4((v0 >> 7) & 127, (v1 >> 7) & 127,
                                                 (v2 >> 7) & 127, (v3 >> 7) & 127);
            *(unsigned*)&lds[2 * APL + wa] = pk4(v0 >> 14, v1 >> 14, v2 >> 14, v3 >> 14);
        }
    }

    // ---- Stage B (144 dwords x 3 planes x 4 byte-phases) ----
    if (l < 144) {
        const int j = JB + 4 * l;
        const unsigned u0 = ldv(B, j),     u1 = ldv(B, j + 1), u2 = ldv(B, j + 2);
        const unsigned u3 = ldv(B, j + 3), u4 = ldv(B, j + 4), u5 = ldv(B, j + 5);
        const unsigned u6 = ldv(B, j + 6);
        const int wb = BOFF + 4 * l;
#define BPLANE(q, D0, D1, D2, D3, D4, D5, D6)                                   \
        *(unsigned*)&lds[wb + ((q)*4 + 0) * BPL] = pk4(D0, D1, D2, D3);         \
        *(unsigned*)&lds[wb + ((q)*4 + 1) * BPL] = pk4(D1, D2, D3, D4);         \
        *(unsigned*)&lds[wb + ((q)*4 + 2) * BPL] = pk4(D2, D3, D4, D5);         \
        *(unsigned*)&lds[wb + ((q)*4 + 3) * BPL] = pk4(D3, D4, D5, D6);
        BPLANE(0, u0 & 127, u1 & 127, u2 & 127, u3 & 127, u4 & 127, u5 & 127, u6 & 127)
        BPLANE(1, (u0 >> 7) & 127, (u1 >> 7) & 127, (u2 >> 7) & 127,
                  (u3 >> 7) & 127, (u4 >> 7) & 127, (u5 >> 7) & 127, (u6 >> 7) & 127)
        BPLANE(2, u0 >> 14, u1 >> 14, u2 >> 14, u3 >> 14, u4 >> 14, u5 >> 14, u6 >> 14)
#undef BPLANE
    }
    __syncthreads();

    const int wv = l >> 6;
    const int ll = l & 63;
    const int n  = ll & 31, h = ll >> 5;
    const int aInv = 1472 + 16 * h - 32 * n;
    const int bInv = BOFF + (n & 3) * BPL + 4 * (120 + 4 * h + (n >> 2));

#pragma unroll 1
    for (int pass = 0; pass < 2; ++pass) {
        i32x16 acc0 = z16(), acc1 = z16(), acc2 = z16(), acc3 = z16(), acc4 = z16();

#pragma unroll
        for (int j = 0; j < 4; ++j) {
            const int s = wv + 4 * j;
            const int aa = swzA(aInv - 32 * s);
            const i32x4 a0 = *(const i32x4*)&lds[0 * APL + aa];
            const i32x4 a1 = *(const i32x4*)&lds[1 * APL + aa];
            const i32x4 a2 = *(const i32x4*)&lds[2 * APL + aa];
            const int bb = bInv - 32 * s;
            i32x4 b0, b1, b2;
#pragma unroll
            for (int q = 0; q < 4; ++q) {
                b0[q] = *(const int*)&lds[bb + 0 * 4 * BPL + 4 * q];
                b1[q] = *(const int*)&lds[bb + 1 * 4 * BPL + 4 * q];
                b2[q] = *(const int*)&lds[bb + 2 * 4 * BPL + 4 * q];
            }
            acc0 = __builtin_amdgcn_mfma_i32_32x32x32_i8(a0, b0, acc0, 0, 0, 0);
            acc1 = __builtin_amdgcn_mfma_i32_32x32x32_i8(a0, b1, acc1, 0, 0, 0);
            acc2 = __builtin_amdgcn_mfma_i32_32x32x32_i8(a0, b2, acc2, 0, 0, 0);
            acc3 = __builtin_amdgcn_mfma_i32_32x32x32_i8(a1, b2, acc3, 0, 0, 0);
            acc4 = __builtin_amdgcn_mfma_i32_32x32x32_i8(a2, b2, acc4, 0, 0, 0);
            acc1 = __builtin_amdgcn_mfma_i32_32x32x32_i8(a1, b0, acc1, 0, 0, 0);
            acc2 = __builtin_amdgcn_mfma_i32_32x32x32_i8(a1, b1, acc2, 0, 0, 0);
            acc3 = __builtin_amdgcn_mfma_i32_32x32x32_i8(a2, b1, acc3, 0, 0, 0);
            acc2 = __builtin_amdgcn_mfma_i32_32x32x32_i8(a2, b0, acc2, 0, 0, 0);
        }

        // Park digit-combined values (pass0's write is an observable LDS use;
        // pass1 overwrites the same slots with identical values).
#pragma unroll
        for (int r = 0; r < 16; ++r) {
            const unsigned v = (unsigned)acc0[r]
                             + ((unsigned)acc1[r] << 7)
                             + ((unsigned)acc2[r] << 14)
                             + ((unsigned)acc3[r] << 21)
                             + ((unsigned)acc4[r] << 28);
            const int idx = 32 * ((r & 3) + 8 * (r >> 2) + 4 * h) + n;
            red[(wv << 10) + idx] = v;
        }
        __syncthreads();
    }

    // Cross-wave sum: lane l owns bins 4l..4l+3.
    const uint4* rb = (const uint4*)red;
    uint4 t0 = rb[l], t1 = rb[256 + l], t2 = rb[512 + l], t3 = rb[768 + l];
    const uint4 tot = make_uint4(t0.x + t1.x + t2.x + t3.x,
                                 t0.y + t1.y + t2.y + t3.y,
                                 t0.z + t1.z + t2.z + t3.z,
                                 t0.w + t1.w + t2.w + t3.w);
    if (PARTIAL) {
        *(uint4*)&part[((size_t)blockIdx.x << 10) + 4 * l] = tot;
    } else {
        unsigned* o = out + c0 + 4 * l;
        atomicAdd(&o[0], tot.x); atomicAdd(&o[1], tot.y);
        atomicAdd(&o[2], tot.z); atomicAdd(&o[3], tot.w);
    }
}

// out[c] = sum over the owning block's unit slices (mod 2^32).
__global__ __launch_bounds__(256) void reduce_k(
    const unsigned* __restrict__ part, unsigned* __restrict__ out)
{
    const int c = (int)blockIdx.x * 256 + (int)threadIdx.x;
    const int blk = c >> 10;

    int base = 0, un = 0, Is = 0;
#pragma unroll 1
    for (int b = 0; b < NBC; ++b) {
        blk_params(b, &Is, &un);
        if (b == blk) break;
        base += un;
    }

    const unsigned* p = part + ((size_t)base << 10) + (c & 1023);
    unsigned s0 = 0, s1 = 0, s2 = 0, s3 = 0;
    int i = 0;
#pragma unroll 1
    for (; i + 4 <= un; i += 4) {
        s0 += p[(size_t)(i + 0) << 10]; s1 += p[(size_t)(i + 1) << 10];
        s2 += p[(size_t)(i + 2) << 10]; s3 += p[(size_t)(i + 3) << 10];
    }
    for (; i < un; ++i) s0 += p[(size_t)i << 10];
    out[c] = s0 + s1 + s2 + s3;
}

extern "C" void kernel_launch(void* const* d_in, const int* in_sizes, int n_in,
                              void* d_out, int out_size, void* d_ws, size_t ws_size,
                              hipStream_t stream)
{
    const int* A = (const int*)d_in[0];
    const int* B = (const int*)d_in[1];
    unsigned* out = (unsigned*)d_out;
    unsigned* ws = (unsigned*)d_ws;

    int NU = 0;
    for (int b = 0; b < NBC; ++b) {
        int Is, un;
        blk_params(b, &Is, &un);
        NU += un;
    }

    const size_t need = (size_t)NU * 1024 * sizeof(unsigned);
    if (ws_size >= need) {
        conv_mfma<true><<<NU, TPB, 0, stream>>>(A, B, ws, out);
        reduce_k<<<OUTN / 256, 256, 0, stream>>>(ws, out);
    } else {
        hipMemsetAsync(d_out, 0, (size_t)out_size * sizeof(int), stream);
        conv_mfma<false><<<NU, TPB, 0, stream>>>(A, B, nullptr, out);
    }
}